// Round 8
// baseline (262.614 us; speedup 1.0000x reference)
//
#include <hip/hip_runtime.h>
#include <hip/hip_bf16.h>

// SpatialAttention: B=4, H=W=64, C=D=256. N=4096 tokens/batch.
// fp32->bf16, QKV proj (MFMA, W staged in LDS), split-K flash attn with
// swapped QK (S^T C-layout -> packed b64 P writes, scalar lsum), P double-
// buffered ACROSS the barrier (1 sync/iter: QK writes P[p], PV consumes
// P[p^1] from previous iter), PV ordered after QK so vf global-load latency
// hides behind QK MFMA. Ks dbuf via global_load_lds. No-max softmax =>
// unnormalized partials add; combine folded into out-proj. XCD swizzle:
// (b,ks) pair in fast grid dim so same-K/V blocks share an XCD's L2.

typedef __attribute__((ext_vector_type(8))) short short8;
typedef __attribute__((ext_vector_type(4))) short short4v;
typedef __attribute__((ext_vector_type(4))) float floatx4;

#define NB 4
#define NT 4096
#define CD 256
#define MTOT (NB * NT)   // 16384

__device__ __forceinline__ short bf16s(float f) {
    union { float f; unsigned u; } a; a.f = f;
    unsigned u = a.u;
    return (short)((u + 0x7fffu + ((u >> 16) & 1u)) >> 16);   // RNE
}

__device__ __forceinline__ float bf2f(short s) {
    union { unsigned u; float f; } a;
    a.u = ((unsigned)(unsigned short)s) << 16;
    return a.f;
}

__device__ __forceinline__ short8 ld8(const short* p) {
    return *(const short8*)p;
}

__device__ __forceinline__ floatx4 mfma16(short8 a, short8 b, floatx4 c) {
    return __builtin_amdgcn_mfma_f32_16x16x32_bf16(a, b, c, 0, 0, 0);
}

// async global->LDS DMA, 16 B/lane; LDS dest = wave-uniform base + lane*16
__device__ __forceinline__ void dma16(const void* g, void* l) {
    __builtin_amdgcn_global_load_lds(
        (const __attribute__((address_space(1))) void*)g,
        (__attribute__((address_space(3))) void*)l, 16, 0, 0);
}

// ---- convert features fp32 -> bf16 [16384 x 256] row-major ----
__global__ __launch_bounds__(256) void k_convx(const float* __restrict__ x,
                                               short* __restrict__ xb) {
    int i = (blockIdx.x * 256 + threadIdx.x) * 4;
    float4 v = *(const float4*)(x + i);
    short4v o;
    o.x = bf16s(v.x); o.y = bf16s(v.y); o.z = bf16s(v.z); o.w = bf16s(v.w);
    *(short4v*)(xb + i) = o;
}

// ---- convert + transpose weights: Wt[z][n][c] = W_z[c][n], bf16 ----
__global__ __launch_bounds__(256) void k_convw(const float* __restrict__ w0,
                                               const float* __restrict__ w1,
                                               const float* __restrict__ w2,
                                               const float* __restrict__ w3,
                                               short* __restrict__ wt) {
    int z = blockIdx.y;
    const float* w = (z == 0) ? w0 : (z == 1) ? w1 : (z == 2) ? w2 : w3;
    int c = blockIdx.x;
    int n = threadIdx.x;
    wt[z * 65536 + n * 256 + c] = bf16s(w[c * 256 + n]);
}

// ---- fused QKV projection: block = 256 thr = 4 waves, 128m x 64n tile ----
__global__ __launch_bounds__(256) void k_proj3(const short* __restrict__ A,
                                               const short* __restrict__ Wt,
                                               const float* __restrict__ bq,
                                               const float* __restrict__ bk,
                                               const float* __restrict__ bv,
                                               short* __restrict__ Qb,
                                               short* __restrict__ Kb,
                                               short* __restrict__ Vt) {
    __shared__ __align__(16) short Ws[16384];
    int z = blockIdx.z;
    const short* W = Wt + z * 65536;
    const float* bias = (z == 0) ? bq : (z == 1) ? bk : bv;
    float scale = (z == 0) ? 0.0625f : 1.0f;   // fold 1/sqrt(256) into Q
    int m0 = blockIdx.x * 128;
    int n0 = blockIdx.y * 64;
    int tid = threadIdx.x;
    int w = tid >> 6, l = tid & 63, r = l & 15, q = l >> 4;

#pragma unroll
    for (int cg = 0; cg < 8; ++cg)
        dma16(W + (size_t)(n0 + w * 16 + r) * CD + (cg * 4 + q) * 8,
              &Ws[w * 4096 + cg * 512]);
    __syncthreads();

    const short* a0 = A + (size_t)(m0 + w * 32 + r) * CD;
    const short* a1 = a0 + 16 * CD;
    floatx4 acc[2][4];
#pragma unroll
    for (int rt = 0; rt < 2; ++rt)
#pragma unroll
        for (int j = 0; j < 4; ++j) acc[rt][j] = (floatx4){0.f, 0.f, 0.f, 0.f};
#pragma unroll
    for (int c = 0; c < 8; ++c) {
        short8 af0 = ld8(a0 + c * 32 + q * 8);
        short8 af1 = ld8(a1 + c * 32 + q * 8);
#pragma unroll
        for (int j = 0; j < 4; ++j) {
            short8 wf = ld8(&Ws[j * 4096 + c * 512 + l * 8]);
            acc[0][j] = mfma16(af0, wf, acc[0][j]);
            acc[1][j] = mfma16(af1, wf, acc[1][j]);
        }
    }
#pragma unroll
    for (int rt = 0; rt < 2; ++rt)
#pragma unroll
        for (int j = 0; j < 4; ++j) {
            int col = n0 + j * 16 + r;
            float bvv = bias[col];
#pragma unroll
            for (int i = 0; i < 4; ++i) {
                int row = m0 + w * 32 + rt * 16 + q * 4 + i;
                short s = bf16s((acc[rt][j][i] + bvv) * scale);
                if (z == 0) Qb[(size_t)row * CD + col] = s;
                else if (z == 1) Kb[(size_t)row * CD + col] = s;
                else {
                    int bb = row >> 12, lm = row & (NT - 1);
                    Vt[((size_t)bb * CD + col) * NT + lm] = s;
                }
            }
        }
}

// ---- split-K flash attention, BM=64, BN=32, 4 waves, 1 barrier/iter ----
// grid (NB*nks, 64). Wave w: QK-swap rows m0+w*16..+16 vs 32 tokens ->
// exp -> packed b64 write into P[it&1]; PV consumes P[(it-1)&1] (prev iter,
// visible via loop-top sync) with vf loaded this iter but AFTER-QK consumed.
__global__ __launch_bounds__(256, 3) void k_attn(const short* __restrict__ Qb,
                                                 const short* __restrict__ Kb,
                                                 const short* __restrict__ Vt,
                                                 short* __restrict__ Op0,
                                                 short* __restrict__ Op1,
                                                 short* __restrict__ Op2,
                                                 float* __restrict__ Lp,
                                                 int nks) {
    __shared__ __align__(16) short Ks[2][8192];   // 2 x 16 KB
    __shared__ __align__(16) short P[2][64][36];  // dbuf, [row][tok] pad 4

    const int tid = threadIdx.x;
    const int w = tid >> 6;
    const int l = tid & 63;
    const int r = l & 15, q = l >> 4;
    const int pair = blockIdx.x;          // fast dim -> XCD round-robin
    const int b = pair / nks;
    const int ks = pair - b * nks;
    const int m0 = blockIdx.y * 64;
    // token range: 128 units of 32 tokens split across nks
    const int qq = 128 / nks, rem = 128 % nks;
    const int u0 = ks * qq + (ks < rem ? ks : rem);
    const int cnt = qq + (ks < rem ? 1 : 0);
    const int t0 = u0 * 32;
    const int tt_d = w & 1;               // DMA token-subtile
    const int cb_d = (w >> 1) * 4;        // DMA chunk-group base
    const short* Qp = Qb + (size_t)b * NT * CD;
    const short* Kp = Kb + (size_t)b * NT * CD;
    const short* Vp = Vt + (size_t)b * CD * NT;   // [256][4096]
    short* Op = (ks == 0) ? Op0 : (ks == 1) ? Op1 : Op2;

    // Q fragments (B-operand): rows m0 + w*16 + r, Q pre-scaled by 1/16
    short8 qf[8];
#pragma unroll
    for (int c = 0; c < 8; ++c)
        qf[c] = ld8(Qp + (size_t)(m0 + w * 16 + r) * CD + c * 32 + q * 8);

    floatx4 o[4][4];
#pragma unroll
    for (int rt = 0; rt < 4; ++rt)
#pragma unroll
        for (int dt = 0; dt < 4; ++dt) o[rt][dt] = (floatx4){0.f, 0.f, 0.f, 0.f};
    float ls = 0.f;
    short8 vf[4];

    auto dma_tile = [&](int p, int n0) {
#pragma unroll
        for (int j = 0; j < 4; ++j)
            dma16(Kp + (size_t)(n0 + tt_d * 16 + r) * CD + ((cb_d + j) * 4 + q) * 8,
                  &Ks[p][tt_d * 4096 + (cb_d + j) * 512]);
    };
    auto ldvf = [&](int n0) {
#pragma unroll
        for (int dt = 0; dt < 4; ++dt)
            vf[dt] = ld8(Vp + (size_t)(w * 64 + dt * 16 + r) * NT + n0 + q * 8);
    };
    auto qk_step = [&](int p) {
        floatx4 s0 = {0.f, 0.f, 0.f, 0.f};
        floatx4 s1 = {0.f, 0.f, 0.f, 0.f};
        const short* kb = &Ks[p][l * 8];
#pragma unroll
        for (int c = 0; c < 8; ++c) {
            s0 = mfma16(ld8(kb + c * 512), qf[c], s0);
            s1 = mfma16(ld8(kb + 4096 + c * 512), qf[c], s1);
        }
#pragma unroll
        for (int tt = 0; tt < 2; ++tt) {
            floatx4 sv = tt ? s1 : s0;
            float e0 = __expf(sv[0]), e1 = __expf(sv[1]);
            float e2 = __expf(sv[2]), e3 = __expf(sv[3]);
            ls += (e0 + e1) + (e2 + e3);
            short4v pk;
            pk.x = bf16s(e0); pk.y = bf16s(e1); pk.z = bf16s(e2); pk.w = bf16s(e3);
            *(short4v*)&P[p][w * 16 + r][tt * 16 + q * 4] = pk;
        }
    };
    auto pv_step = [&](int p) {
#pragma unroll
        for (int rt = 0; rt < 4; ++rt) {
            short8 pf = ld8(&P[p][rt * 16 + r][q * 8]);
#pragma unroll
            for (int dt = 0; dt < 4; ++dt)
                o[rt][dt] = mfma16(pf, vf[dt], o[rt][dt]);
        }
    };

    // prologue: DMA K tile 0
    dma_tile(0, t0);

#pragma unroll 1
    for (int it = 0; it < cnt; ++it) {
        const int p = it & 1;
        __syncthreads();   // Ks[p] DMA done; P[p^1] (iter it-1) visible
        if (it > 0) ldvf(t0 + (it - 1) * 32);     // V for PREV block; used after QK
        if (it + 1 < cnt) dma_tile(p ^ 1, t0 + (it + 1) * 32);
        qk_step(p);                                // Ks[p] -> P[p]
        if (it > 0) pv_step(p ^ 1);                // P[p^1] x vf (block it-1)
    }
    // epilogue: consume last P
    __syncthreads();
    ldvf(t0 + (cnt - 1) * 32);
    pv_step((cnt - 1) & 1);

    // partial lsum: lane (r,q) holds row m0+w*16+r partial; reduce across q
    ls += __shfl_xor(ls, 16);
    ls += __shfl_xor(ls, 32);
    if (l < 16)
        Lp[(size_t)ks * MTOT + b * NT + m0 + w * 16 + l] = ls;

    // unnormalized partial O store (cols w*64..+64, all 64 rows)
#pragma unroll
    for (int rt = 0; rt < 4; ++rt)
#pragma unroll
        for (int i = 0; i < 4; ++i) {
            int row = m0 + rt * 16 + q * 4 + i;
#pragma unroll
            for (int dt = 0; dt < 4; ++dt)
                Op[((size_t)b * NT + row) * CD + w * 64 + dt * 16 + r] =
                    bf16s(o[rt][dt][i]);
        }
}

// ---- output projection + split-K combine: A = (sum Opk)/(sum lk), fp32 out
__global__ __launch_bounds__(256) void k_oproj(const short* __restrict__ Op0,
                                               const short* __restrict__ Op1,
                                               const short* __restrict__ Op2,
                                               const float* __restrict__ Lp,
                                               const short* __restrict__ Wot,
                                               const float* __restrict__ bo,
                                               float* __restrict__ out, int nks) {
    __shared__ __align__(16) short Ws[16384];
    int m0 = blockIdx.x * 128;
    int n0 = blockIdx.y * 64;
    int tid = threadIdx.x;
    int w = tid >> 6, l = tid & 63, r = l & 15, q = l >> 4;

#pragma unroll
    for (int cg = 0; cg < 8; ++cg)
        dma16(Wot + (size_t)(n0 + w * 16 + r) * CD + (cg * 4 + q) * 8,
              &Ws[w * 4096 + cg * 512]);
    __syncthreads();

    int row0 = m0 + w * 32 + r;
    float lt0 = Lp[row0] + Lp[MTOT + row0];
    float lt1 = Lp[row0 + 16] + Lp[MTOT + row0 + 16];
    if (nks == 3) { lt0 += Lp[2 * MTOT + row0]; lt1 += Lp[2 * MTOT + row0 + 16]; }
    float inv0 = 1.0f / lt0, inv1 = 1.0f / lt1;
    const short* p00 = Op0 + (size_t)row0 * CD;
    const short* p01 = Op1 + (size_t)row0 * CD;
    const short* p02 = Op2 + (size_t)row0 * CD;
    floatx4 acc[2][4];
#pragma unroll
    for (int rt = 0; rt < 2; ++rt)
#pragma unroll
        for (int j = 0; j < 4; ++j) acc[rt][j] = (floatx4){0.f, 0.f, 0.f, 0.f};
#pragma unroll
    for (int c = 0; c < 8; ++c) {
        int off0 = c * 32 + q * 8, off1 = 16 * CD + c * 32 + q * 8;
        short8 x0 = ld8(p00 + off0), y0 = ld8(p01 + off0);
        short8 x1 = ld8(p00 + off1), y1 = ld8(p01 + off1);
        short8 af0, af1;
        if (nks == 3) {
            short8 z0 = ld8(p02 + off0), z1 = ld8(p02 + off1);
#pragma unroll
            for (int jj = 0; jj < 8; ++jj) {
                af0[jj] = bf16s((bf2f(x0[jj]) + bf2f(y0[jj]) + bf2f(z0[jj])) * inv0);
                af1[jj] = bf16s((bf2f(x1[jj]) + bf2f(y1[jj]) + bf2f(z1[jj])) * inv1);
            }
        } else {
#pragma unroll
            for (int jj = 0; jj < 8; ++jj) {
                af0[jj] = bf16s((bf2f(x0[jj]) + bf2f(y0[jj])) * inv0);
                af1[jj] = bf16s((bf2f(x1[jj]) + bf2f(y1[jj])) * inv1);
            }
        }
#pragma unroll
        for (int j = 0; j < 4; ++j) {
            short8 wf = ld8(&Ws[j * 4096 + c * 512 + l * 8]);
            acc[0][j] = mfma16(af0, wf, acc[0][j]);
            acc[1][j] = mfma16(af1, wf, acc[1][j]);
        }
    }
#pragma unroll
    for (int rt = 0; rt < 2; ++rt)
#pragma unroll
        for (int j = 0; j < 4; ++j) {
            int col = n0 + j * 16 + r;
            float bvv = bo[col];
#pragma unroll
            for (int i = 0; i < 4; ++i)
                out[(size_t)(m0 + w * 32 + rt * 16 + q * 4 + i) * CD + col] =
                    acc[rt][j][i] + bvv;
        }
}

extern "C" void kernel_launch(void* const* d_in, const int* in_sizes, int n_in,
                              void* d_out, int out_size, void* d_ws, size_t ws_size,
                              hipStream_t stream) {
    const float* x  = (const float*)d_in[0];
    const float* Wq = (const float*)d_in[1];
    const float* bq = (const float*)d_in[2];
    const float* Wk = (const float*)d_in[3];
    const float* bk = (const float*)d_in[4];
    const float* Wv = (const float*)d_in[5];
    const float* bv = (const float*)d_in[6];
    const float* Wo = (const float*)d_in[7];
    const float* bo = (const float*)d_in[8];
    float* out = (float*)d_out;

    char* ws = (char*)d_ws;
    const size_t MB = 1024u * 1024u;
    short* xb  = (short*)(ws);             // 8 MB: x bf16; DEAD after proj3 ->
    short* Op0 = (short*)(ws);             //        reused as partial-O (ks=0)
    short* Qb  = (short*)(ws + 8 * MB);    // 8 MB: Q*scale bf16
    short* Kb  = (short*)(ws + 16 * MB);   // 8 MB: K bf16
    short* Vt  = (short*)(ws + 24 * MB);   // 8 MB: V^T bf16 [4][256][4096]
    short* Op1 = (short*)(ws + 32 * MB);   // 8 MB: partial-O (ks=1)
    short* Wt  = (short*)(ws + 40 * MB);   // 512 KB: transposed weights bf16
    float* Lp  = (float*)(ws + 40 * MB + 512 * 1024);  // 192 KB: partial l [3][16384]
    short* Op2 = (short*)(ws + 41 * MB);   // 8 MB: partial-O (ks=2), if ws allows

    // 3-way split-K (768 blocks = 3/CU) when workspace permits, else 2-way.
    int nks = (ws_size >= 49 * MB + 512 * 1024) ? 3 : 2;
    if (nks == 2) Op2 = Op1;   // unused, keep pointer valid

    k_convx<<<dim3(MTOT * CD / (256 * 4)), 256, 0, stream>>>(x, xb);
    k_convw<<<dim3(256, 4), 256, 0, stream>>>(Wq, Wk, Wv, Wo, Wt);
    k_proj3<<<dim3(MTOT / 128, CD / 64, 3), 256, 0, stream>>>(xb, Wt, bq, bk, bv, Qb, Kb, Vt);
    k_attn<<<dim3(NB * nks, NT / 64), 256, 0, stream>>>(Qb, Kb, Vt, Op0, Op1, Op2, Lp, nks);
    k_oproj<<<dim3(MTOT / 128, CD / 64), 256, 0, stream>>>(Op0, Op1, Op2, Lp, Wt + 196608, bo, out, nks);
}